// Round 9
// baseline (60.929 us; speedup 1.0000x reference)
//
#include <hip/hip_runtime.h>
#include <hip/hip_bf16.h>

typedef __bf16 bf16x8 __attribute__((ext_vector_type(8)));
typedef float  f32x4  __attribute__((ext_vector_type(4)));
typedef unsigned short u16;
typedef unsigned int   u32;

__device__ __forceinline__ u16 f2b(float x) {
  __bf16 b = (__bf16)x;
  return __builtin_bit_cast(u16, b);
}

__device__ __forceinline__ void gload_lds16(const u16* g, u16* l) {
  __builtin_amdgcn_global_load_lds(
      (const __attribute__((address_space(1))) void*)g,
      (__attribute__((address_space(3))) void*)l, 16, 0, 0);
}

// pack 8 f32 -> 8 bf16, one ds_write_b128
__device__ __forceinline__ void cvt8_store(u16* dst, float4 a, float4 b) {
  union { u16 u[8]; uint4 v; } r;
  r.u[0] = f2b(a.x); r.u[1] = f2b(a.y); r.u[2] = f2b(a.z); r.u[3] = f2b(a.w);
  r.u[4] = f2b(b.x); r.u[5] = f2b(b.y); r.u[6] = f2b(b.z); r.u[7] = f2b(b.w);
  *(uint4*)dst = r.v;
}

// ---------------- prep: transpose + cvt the 4 weight matrices only -----------
__global__ __launch_bounds__(256) void prep_kernel(
    const float* __restrict__ W0, const float* __restrict__ W1,
    const float* __restrict__ W2, const float* __restrict__ W3,
    u16* __restrict__ T0, u16* __restrict__ T1, u16* __restrict__ T2, u16* __restrict__ T3)
{
  __shared__ float tile[32][33];
  int t = blockIdx.x;
  int z = t >> 10, rem = t & 1023;
  const float* W = (z == 0) ? W0 : (z == 1) ? W1 : (z == 2) ? W2 : W3;
  u16* T = (z == 0) ? T0 : (z == 1) ? T1 : (z == 2) ? T2 : T3;
  int tx = threadIdx.x & 31, ty = threadIdx.x >> 5;
  int c0 = (rem & 31) << 5, r0 = (rem >> 5) << 5;
#pragma unroll
  for (int i = 0; i < 4; ++i)
    tile[ty + i * 8][tx] = W[(size_t)(r0 + ty + i * 8) * 1024 + c0 + tx];
  __syncthreads();
#pragma unroll
  for (int i = 0; i < 4; ++i)
    T[(size_t)(c0 + ty + i * 8) * 1024 + r0 + tx] = f2b(tile[tx][ty + i * 8]);
}

// ---------------- shared GEMM pieces (R3-proven 128x128, 4 waves) ------------
__device__ __forceinline__ void compute_step(
    const u16* asc, const u16* bsc, int lane, int wm, int wn, f32x4 (&acc)[4][4])
{
#pragma unroll
  for (int kk = 0; kk < 2; ++kk) {
    bf16x8 af[4], bfr[4];
    int colb = (kk << 6) + ((lane >> 4) << 4);  // byte col within 128B row
#pragma unroll
    for (int m = 0; m < 4; ++m) {
      int r = (wm << 6) + (m << 4) + (lane & 15);
      af[m] = *(const bf16x8*)((const char*)asc + (r << 7) + (colb ^ ((r & 7) << 4)));
    }
#pragma unroll
    for (int n = 0; n < 4; ++n) {
      int r = (wn << 6) + (n << 4) + (lane & 15);
      bfr[n] = *(const bf16x8*)((const char*)bsc + (r << 7) + (colb ^ ((r & 7) << 4)));
    }
#pragma unroll
    for (int m = 0; m < 4; ++m)
#pragma unroll
      for (int n = 0; n < 4; ++n)
        acc[m][n] = __builtin_amdgcn_mfma_f32_16x16x32_bf16(af[m], bfr[n], acc[m][n], 0, 0, 0);
  }
}

__device__ __forceinline__ void stage_b(const u16* gB, u16* bs, int wave, int K, int k0) {
#pragma unroll
  for (int i = 0; i < 4; ++i) {
    int rb = (wave << 5) + (i << 3);
    gload_lds16(gB + (size_t)(i << 3) * K + k0, bs + (rb << 6));
  }
}

template <int OUTF32>
__device__ __forceinline__ void cwrite(
    void* C, int N, int row0, int col0, int lane, int wm, int wn, f32x4 (&acc)[4][4])
{
  const int crow = (lane >> 4) << 2;
  const int ccol = lane & 15;
#pragma unroll
  for (int m = 0; m < 4; ++m) {
#pragma unroll
    for (int n = 0; n < 4; ++n) {
      int r = row0 + (wm << 6) + (m << 4) + crow;
      int c = col0 + (wn << 6) + (n << 4) + ccol;
#pragma unroll
      for (int reg = 0; reg < 4; ++reg) {
        if (OUTF32) ((float*)C)[(size_t)(r + reg) * N + c] = acc[m][n][reg];
        else        ((u16*)C)[(size_t)(r + reg) * N + c] = f2b(acc[m][n][reg]);
      }
    }
  }
}

// ---------------- GEMM core, bf16 A via gload_lds (outproj) -----------------
template <int OUTF32>
__device__ __forceinline__ void gemm_core(
    const u16* __restrict__ A, const u16* __restrict__ Bt, void* __restrict__ C,
    int N, int K, int row0, int col0,
    u16* As0, u16* As1, u16* Bs0, u16* Bs1)
{
  const int tid = threadIdx.x;
  const int wave = tid >> 6, lane = tid & 63;
  const int wm = wave >> 1, wn = wave & 1;
  f32x4 acc[4][4] = {};

  const int srow = lane >> 3, sslot = lane & 7;
  const int scol = ((sslot ^ srow) << 3);  // pre-swizzled source col
  const u16* gA = A + (size_t)(row0 + (wave << 5) + srow) * K + scol;
  const u16* gB = Bt + (size_t)(col0 + (wave << 5) + srow) * K + scol;

  stage_b(gA, As0, wave, K, 0);
  stage_b(gB, Bs0, wave, K, 0);
  __syncthreads();

  u16 *asc = As0, *bsc = Bs0, *asn = As1, *bsn = Bs1;
  for (int k0 = 0; k0 < K; k0 += 64) {
    if (k0 + 64 < K) {
      stage_b(gA, asn, wave, K, k0 + 64);
      stage_b(gB, bsn, wave, K, k0 + 64);
    }
    compute_step(asc, bsc, lane, wm, wn, acc);
    __syncthreads();
    u16* t_;
    t_ = asc; asc = asn; asn = t_;
    t_ = bsc; bsc = bsn; bsn = t_;
  }
  cwrite<OUTF32>(C, N, row0, col0, lane, wm, wn, acc);
}

// ---------------- GEMM core, f32 A reg-staged + cvt (projections) ------------
// Single barrier per K-step: cvt'd A(k+1) and B(k+1) go into the NEXT buffer
// BEFORE compute(k) (disjoint from the buffer being read); the one barrier
// drains both and flips.
__device__ __forceinline__ void gemm_core_f32a(
    const float* __restrict__ Af,    // pre-offset to row0 of this tile
    const u16* __restrict__ Bt, u16* __restrict__ C,
    int N, int K, int row0, int col0,
    u16* As0, u16* As1, u16* Bs0, u16* Bs1)
{
  const int tid = threadIdx.x;
  const int wave = tid >> 6, lane = tid & 63;
  const int wm = wave >> 1, wn = wave & 1;
  f32x4 acc[4][4] = {};

  const int srow = lane >> 3, sslot = lane & 7;
  const int scol = ((sslot ^ srow) << 3);
  const float* gAf = Af + (size_t)((wave << 5) + srow) * K + scol;
  const u16*  gB  = Bt + (size_t)(col0 + (wave << 5) + srow) * K + scol;
  const int awbase = (lane << 3);

  float4 a0[4], a1[4];
  // prologue: tile 0 staged, then preload tile 1 regs
#pragma unroll
  for (int i = 0; i < 4; ++i) {
    const float* g = gAf + (size_t)(i << 3) * K;
    a0[i] = *(const float4*)g; a1[i] = *(const float4*)(g + 4);
  }
  stage_b(gB, Bs0, wave, K, 0);
#pragma unroll
  for (int i = 0; i < 4; ++i)
    cvt8_store(As0 + (((wave << 5) + (i << 3)) << 6) + awbase, a0[i], a1[i]);
  __syncthreads();
#pragma unroll
  for (int i = 0; i < 4; ++i) {
    const float* g = gAf + (size_t)(i << 3) * K + 64;
    a0[i] = *(const float4*)g; a1[i] = *(const float4*)(g + 4);
  }

  u16 *asc = As0, *bsc = Bs0, *asn = As1, *bsn = Bs1;
  for (int k0 = 0; k0 < K; k0 += 64) {
    const bool more = (k0 + 64) < K;
    if (more) {
      // write A(k+1) into next buffer (nobody reads asn until after barrier)
#pragma unroll
      for (int i = 0; i < 4; ++i)
        cvt8_store(asn + (((wave << 5) + (i << 3)) << 6) + awbase, a0[i], a1[i]);
      stage_b(gB, bsn, wave, K, k0 + 64);   // B prefetch flies under MFMA
      if (k0 + 128 < K) {
        // issue A(k+2) loads early; latency hides under compute + barrier
#pragma unroll
        for (int i = 0; i < 4; ++i) {
          const float* g = gAf + (size_t)(i << 3) * K + (k0 + 128);
          a0[i] = *(const float4*)g; a1[i] = *(const float4*)(g + 4);
        }
      }
    }
    compute_step(asc, bsc, lane, wm, wn, acc);
    __syncthreads();                         // drains B gloads + A ds_writes
    u16* t_;
    t_ = asc; asc = asn; asn = t_;
    t_ = bsc; bsc = bsn; bsn = t_;
  }
  cwrite<0>(C, N, row0, col0, lane, wm, wn, acc);
}

// out projection (f32 out), 256 blocks, XCD-swizzled
template <int OUTF32>
__global__ __launch_bounds__(256, 2) void gemm_bt_kernel(
    const u16* __restrict__ A, const u16* __restrict__ Bt, void* __restrict__ C,
    int M, int N, int K)
{
  __shared__ u16 As[2][8192];
  __shared__ u16 Bs[2][8192];
  int bid = blockIdx.x;
  int t = (bid & 7) * 32 + (bid >> 3);      // bijective XCD chunk (256 = 8*32)
  const int bx = t & 7, by = t >> 3;
  gemm_core<OUTF32>(A, Bt, C, N, K, by << 7, bx << 7, As[0], As[1], Bs[0], Bs[1]);
}

// fused Q + K + V projections, f32 A direct (384 blocks), XCD-swizzled
__global__ __launch_bounds__(256, 2) void proj_kernel(
    const float* __restrict__ q, const float* __restrict__ k, const float* __restrict__ v,
    const u16* __restrict__ Wqt, const u16* __restrict__ Wkt, const u16* __restrict__ Wvt,
    u16* __restrict__ Qp, u16* __restrict__ KVp)
{
  __shared__ u16 As[2][8192];
  __shared__ u16 Bs[2][8192];
  int bid = blockIdx.x;
  int t = (bid & 7) * 48 + (bid >> 3);      // bijective XCD chunk (384 = 8*48)
  const float* Af; const u16* Bt; u16* C; int row0, col0;
  if (t < 256) {                            // Q projection: M=4096
    row0 = (t >> 3) << 7; col0 = (t & 7) << 7;
    Af = q + (size_t)row0 * 1024; Bt = Wqt; C = Qp;
  } else {                                  // K/V projections: M=2048
    int t2 = t - 256;
    row0 = (t2 >> 3) << 7; col0 = (t2 & 7) << 7;
    if (row0 < 1024) { Af = k + (size_t)row0 * 1024; Bt = Wkt; }
    else             { Af = v + (size_t)(row0 - 1024) * 1024; Bt = Wvt; }
    C = KVp;
  }
  gemm_core_f32a(Af, Bt, C, 1024, 1024, row0, col0, As[0], As[1], Bs[0], Bs[1]);
}

// ---------------- strided-local attention (MFMA) ------------------------------
// P overlays Ql (wave w reads/writes only rows w*16..w*16+15 of both) with an
// XOR swizzle so the PV ds_read_b128 stays bank-friendly. No barrier between
// softmax and PV: DS ops are in-order per wave, and P rows are wave-private.
#define VTP 56   // Vt pitch (elems)
__global__ __launch_bounds__(256) void attn_kernel(
    const u16* __restrict__ Qp, const u16* __restrict__ Kp,
    const u16* __restrict__ Vp, u16* __restrict__ Ob)
{
  __shared__ u16 Ql[64 * 64];          // Q (swizzled 128B rows), then P overlay
  __shared__ u16 Kl[48 * 64];          // swizzled 128B rows
  __shared__ u16 Vt[64 * VTP + 64];    // V^T [d][c] + zeroed tail

  const int jt = blockIdx.x, h = blockIdx.y, b = blockIdx.z;
  const int j0 = jt << 6;
  const int kbase = (j0 - 124) >> 2;
  const int tid = threadIdx.x;
  const int wave = tid >> 6, lane = tid & 63;

  const int srow = lane >> 3, sslot = lane & 7;
  const int scol = ((sslot ^ srow) << 3);
  for (int g = wave; g < 8; g += 4) {
    int r = (g << 3) + srow;
    const u16* ga = Qp + (((size_t)(b * 2048 + j0 + r)) << 10) + (h << 6) + scol;
    gload_lds16(ga, &Ql[g << 9]);
  }
  for (int g = wave; g < 6; g += 4) {
    int r = (g << 3) + srow;
    int key = kbase + r;
    key = key < 0 ? 0 : (key > 511 ? 511 : key);
    const u16* gk = Kp + (((size_t)(b * 512 + key)) << 10) + (h << 6) + scol;
    gload_lds16(gk, &Kl[g << 9]);
  }
  for (int idx = tid; idx < 48 * 8; idx += 256) {
    int row = idx >> 3, seg = idx & 7;
    int key = kbase + row;
    key = key < 0 ? 0 : (key > 511 ? 511 : key);
    uint4 x = *(const uint4*)(Vp + (((size_t)(b * 512 + key)) << 10) + (h << 6) + (seg << 3));
    int d0 = seg << 3;
    Vt[(d0 + 0) * VTP + row] = (u16)(x.x);
    Vt[(d0 + 1) * VTP + row] = (u16)(x.x >> 16);
    Vt[(d0 + 2) * VTP + row] = (u16)(x.y);
    Vt[(d0 + 3) * VTP + row] = (u16)(x.y >> 16);
    Vt[(d0 + 4) * VTP + row] = (u16)(x.z);
    Vt[(d0 + 5) * VTP + row] = (u16)(x.z >> 16);
    Vt[(d0 + 6) * VTP + row] = (u16)(x.w);
    Vt[(d0 + 7) * VTP + row] = (u16)(x.w >> 16);
  }
  if (tid < 64) *(uint4*)&Vt[tid * VTP + 48] = make_uint4(0, 0, 0, 0);
  else if (tid < 72) *(uint4*)&Vt[64 * VTP + ((tid - 64) << 3)] = make_uint4(0, 0, 0, 0);
  __syncthreads();

  f32x4 sacc[3] = {};
  const int frow_a = (wave << 4) + (lane & 15);
#pragma unroll
  for (int kk = 0; kk < 2; ++kk) {
    int colb = (kk << 6) + ((lane >> 4) << 4);
    bf16x8 aq = *(const bf16x8*)((const char*)Ql + (frow_a << 7) + (colb ^ ((frow_a & 7) << 4)));
#pragma unroll
    for (int nt = 0; nt < 3; ++nt) {
      int rk = (nt << 4) + (lane & 15);
      bf16x8 bk = *(const bf16x8*)((const char*)Kl + (rk << 7) + (colb ^ ((rk & 7) << 4)));
      sacc[nt] = __builtin_amdgcn_mfma_f32_16x16x32_bf16(aq, bk, sacc[nt], 0, 0, 0);
    }
  }

  const int rof = (wave << 2) + (lane >> 4);
  const int cb0 = lane & 15;
  bool vld[3]; float sc[3][4];
#pragma unroll
  for (int nt = 0; nt < 3; ++nt) {
    int c = cb0 + (nt << 4);
    vld[nt] = ((unsigned)(c - rof) < 32u) && (kbase + c >= 0);
#pragma unroll
    for (int r = 0; r < 4; ++r) sc[nt][r] = sacc[nt][r] * 0.125f;
  }
  float mx[4], rs[4];
#pragma unroll
  for (int r = 0; r < 4; ++r) {
    float m = -3.0e38f;
#pragma unroll
    for (int nt = 0; nt < 3; ++nt) m = vld[nt] ? fmaxf(m, sc[nt][r]) : m;
    m = fmaxf(m, __shfl_xor(m, 1));
    m = fmaxf(m, __shfl_xor(m, 2));
    m = fmaxf(m, __shfl_xor(m, 4));
    m = fmaxf(m, __shfl_xor(m, 8));
    mx[r] = m;
  }
#pragma unroll
  for (int r = 0; r < 4; ++r) {
    float s = 0.f;
#pragma unroll
    for (int nt = 0; nt < 3; ++nt) {
      float e = vld[nt] ? __expf(sc[nt][r] - mx[r]) : 0.f;
      sc[nt][r] = e;
      s += e;
    }
    s += __shfl_xor(s, 1);
    s += __shfl_xor(s, 2);
    s += __shfl_xor(s, 4);
    s += __shfl_xor(s, 8);
    rs[r] = 1.f / s;
  }
  // write P (bf16) overlaid on this wave's own Ql rows, XOR-swizzled
#pragma unroll
  for (int r = 0; r < 4; ++r) {
    int jq = (wave << 4) + ((lane >> 4) << 2) + r;
    char* prow = (char*)Ql + (jq << 7);
    int sw = (jq & 7) << 4;
#pragma unroll
    for (int nt = 0; nt < 3; ++nt) {
      int c = cb0 + (nt << 4);
      *(u16*)(prow + (((c << 1)) ^ sw)) = f2b(sc[nt][r] * rs[r]);
    }
    *(u16*)(prow + ((((48 + cb0) << 1)) ^ sw)) = 0;
  }
  // no barrier: P rows are wave-private; DS ops are in-order per wave

  f32x4 oacc[4] = {};
#pragma unroll
  for (int kk = 0; kk < 2; ++kk) {
    int koffb = (kk << 6) + ((lane >> 4) << 4);   // byte offset within 128B row
    bf16x8 ap = *(const bf16x8*)((const char*)Ql + (frow_a << 7) + (koffb ^ ((frow_a & 7) << 4)));
#pragma unroll
    for (int nt = 0; nt < 4; ++nt) {
      int dr = (nt << 4) + (lane & 15);
      bf16x8 bv = *(const bf16x8*)&Vt[dr * VTP + (koffb >> 1)];
      oacc[nt] = __builtin_amdgcn_mfma_f32_16x16x32_bf16(ap, bv, oacc[nt], 0, 0, 0);
    }
  }

#pragma unroll
  for (int nt = 0; nt < 4; ++nt) {
    int d = (nt << 4) + (lane & 15);
#pragma unroll
    for (int r = 0; r < 4; ++r) {
      int jq = (wave << 4) + ((lane >> 4) << 2) + r;
      Ob[(((size_t)(b * 2048 + j0 + jq)) << 10) + (h << 6) + d] = f2b(oacc[nt][r]);
    }
  }
}

extern "C" void kernel_launch(void* const* d_in, const int* in_sizes, int n_in,
                              void* d_out, int out_size, void* d_ws, size_t ws_size,
                              hipStream_t stream) {
  const float* q  = (const float*)d_in[0];
  const float* k  = (const float*)d_in[1];
  const float* v  = (const float*)d_in[2];
  const float* Wq = (const float*)d_in[3];
  const float* Wk = (const float*)d_in[4];
  const float* Wv = (const float*)d_in[5];
  const float* Wo = (const float*)d_in[6];

  char* ws = (char*)d_ws;
  const size_t MB = 1u << 20;
  u16* Wqt = (u16*)(ws + 0 * MB);    // 2 MB
  u16* Wkt = (u16*)(ws + 2 * MB);
  u16* Wvt = (u16*)(ws + 4 * MB);
  u16* Wot = (u16*)(ws + 6 * MB);
  u16* Qp  = (u16*)(ws + 8 * MB);    // 8 MB
  u16* Kp  = (u16*)(ws + 16 * MB);   // 2 MB  (Kp||Vp contiguous)
  u16* Vp  = (u16*)(ws + 18 * MB);   // 2 MB
  u16* Ob  = (u16*)(ws + 20 * MB);   // 8 MB  (total 28 MB)

  // 1) prep: transpose/convert the 4 weight matrices
  prep_kernel<<<4096, 256, 0, stream>>>(Wq, Wk, Wv, Wo, Wqt, Wkt, Wvt, Wot);
  // 2) all three projections, f32 A direct, single-barrier K-loop
  proj_kernel<<<384, 256, 0, stream>>>(q, k, v, Wqt, Wkt, Wvt, Qp, Kp);
  // 3) attention (MFMA, P-overlay, 2 barriers total)
  attn_kernel<<<dim3(32, 16, 2), 256, 0, stream>>>(Qp, Kp, Vp, Ob);
  // 4) output projection (f32 out)
  gemm_bt_kernel<1><<<256, 256, 0, stream>>>(Ob, Wot, d_out, 4096, 1024, 1024);
}

// Round 10
// 58.242 us; speedup vs baseline: 1.0461x; 1.0461x over previous
//
#include <hip/hip_runtime.h>
#include <hip/hip_bf16.h>

typedef __bf16 bf16x8 __attribute__((ext_vector_type(8)));
typedef float  f32x4  __attribute__((ext_vector_type(4)));
typedef unsigned short u16;
typedef unsigned int   u32;

__device__ __forceinline__ u16 f2b(float x) {
  __bf16 b = (__bf16)x;
  return __builtin_bit_cast(u16, b);
}

__device__ __forceinline__ void gload_lds16(const u16* g, u16* l) {
  __builtin_amdgcn_global_load_lds(
      (const __attribute__((address_space(1))) void*)g,
      (__attribute__((address_space(3))) void*)l, 16, 0, 0);
}

// pack 8 f32 -> 8 bf16, one ds_write_b128
__device__ __forceinline__ void cvt8_store(u16* dst, float4 a, float4 b) {
  union { u16 u[8]; uint4 v; } r;
  r.u[0] = f2b(a.x); r.u[1] = f2b(a.y); r.u[2] = f2b(a.z); r.u[3] = f2b(a.w);
  r.u[4] = f2b(b.x); r.u[5] = f2b(b.y); r.u[6] = f2b(b.z); r.u[7] = f2b(b.w);
  *(uint4*)dst = r.v;
}

// shared 32x32 transpose-tile body (used by prep and the attn-appended blocks)
__device__ __forceinline__ void wtile_transpose(
    const float* __restrict__ W, u16* __restrict__ T, int rem, float* tile /*32x33*/)
{
  int tx = threadIdx.x & 31, ty = threadIdx.x >> 5;
  int c0 = (rem & 31) << 5, r0 = (rem >> 5) << 5;
#pragma unroll
  for (int i = 0; i < 4; ++i)
    tile[(ty + i * 8) * 33 + tx] = W[(size_t)(r0 + ty + i * 8) * 1024 + c0 + tx];
  __syncthreads();
#pragma unroll
  for (int i = 0; i < 4; ++i)
    T[(size_t)(c0 + ty + i * 8) * 1024 + r0 + tx] = f2b(tile[tx * 33 + ty + i * 8]);
}

// ---------------- prep: transpose + cvt Wq/Wk/Wv only (Wo moved to attn) -----
__global__ __launch_bounds__(256) void prep_kernel(
    const float* __restrict__ W0, const float* __restrict__ W1,
    const float* __restrict__ W2,
    u16* __restrict__ T0, u16* __restrict__ T1, u16* __restrict__ T2)
{
  __shared__ float tile[32 * 33];
  int t = blockIdx.x;
  int z = t >> 10, rem = t & 1023;
  const float* W = (z == 0) ? W0 : (z == 1) ? W1 : W2;
  u16* T = (z == 0) ? T0 : (z == 1) ? T1 : T2;
  wtile_transpose(W, T, rem, tile);
}

// ---------------- shared GEMM pieces (R3-proven 128x128, 4 waves) ------------
__device__ __forceinline__ void compute_step(
    const u16* asc, const u16* bsc, int lane, int wm, int wn, f32x4 (&acc)[4][4])
{
#pragma unroll
  for (int kk = 0; kk < 2; ++kk) {
    bf16x8 af[4], bfr[4];
    int colb = (kk << 6) + ((lane >> 4) << 4);  // byte col within 128B row
#pragma unroll
    for (int m = 0; m < 4; ++m) {
      int r = (wm << 6) + (m << 4) + (lane & 15);
      af[m] = *(const bf16x8*)((const char*)asc + (r << 7) + (colb ^ ((r & 7) << 4)));
    }
#pragma unroll
    for (int n = 0; n < 4; ++n) {
      int r = (wn << 6) + (n << 4) + (lane & 15);
      bfr[n] = *(const bf16x8*)((const char*)bsc + (r << 7) + (colb ^ ((r & 7) << 4)));
    }
#pragma unroll
    for (int m = 0; m < 4; ++m)
#pragma unroll
      for (int n = 0; n < 4; ++n)
        acc[m][n] = __builtin_amdgcn_mfma_f32_16x16x32_bf16(af[m], bfr[n], acc[m][n], 0, 0, 0);
  }
}

__device__ __forceinline__ void stage_b(const u16* gB, u16* bs, int wave, int K, int k0) {
#pragma unroll
  for (int i = 0; i < 4; ++i) {
    int rb = (wave << 5) + (i << 3);
    gload_lds16(gB + (size_t)(i << 3) * K + k0, bs + (rb << 6));
  }
}

template <int OUTF32>
__device__ __forceinline__ void cwrite(
    void* C, int N, int row0, int col0, int lane, int wm, int wn, f32x4 (&acc)[4][4])
{
  const int crow = (lane >> 4) << 2;
  const int ccol = lane & 15;
#pragma unroll
  for (int m = 0; m < 4; ++m) {
#pragma unroll
    for (int n = 0; n < 4; ++n) {
      int r = row0 + (wm << 6) + (m << 4) + crow;
      int c = col0 + (wn << 6) + (n << 4) + ccol;
#pragma unroll
      for (int reg = 0; reg < 4; ++reg) {
        if (OUTF32) ((float*)C)[(size_t)(r + reg) * N + c] = acc[m][n][reg];
        else        ((u16*)C)[(size_t)(r + reg) * N + c] = f2b(acc[m][n][reg]);
      }
    }
  }
}

// ---------------- GEMM core, bf16 A via gload_lds (outproj) -----------------
template <int OUTF32>
__device__ __forceinline__ void gemm_core(
    const u16* __restrict__ A, const u16* __restrict__ Bt, void* __restrict__ C,
    int N, int K, int row0, int col0,
    u16* As0, u16* As1, u16* Bs0, u16* Bs1)
{
  const int tid = threadIdx.x;
  const int wave = tid >> 6, lane = tid & 63;
  const int wm = wave >> 1, wn = wave & 1;
  f32x4 acc[4][4] = {};

  const int srow = lane >> 3, sslot = lane & 7;
  const int scol = ((sslot ^ srow) << 3);  // pre-swizzled source col
  const u16* gA = A + (size_t)(row0 + (wave << 5) + srow) * K + scol;
  const u16* gB = Bt + (size_t)(col0 + (wave << 5) + srow) * K + scol;

  stage_b(gA, As0, wave, K, 0);
  stage_b(gB, Bs0, wave, K, 0);
  __syncthreads();

  u16 *asc = As0, *bsc = Bs0, *asn = As1, *bsn = Bs1;
  for (int k0 = 0; k0 < K; k0 += 64) {
    if (k0 + 64 < K) {
      stage_b(gA, asn, wave, K, k0 + 64);
      stage_b(gB, bsn, wave, K, k0 + 64);
    }
    compute_step(asc, bsc, lane, wm, wn, acc);
    __syncthreads();
    u16* t_;
    t_ = asc; asc = asn; asn = t_;
    t_ = bsc; bsc = bsn; bsn = t_;
  }
  cwrite<OUTF32>(C, N, row0, col0, lane, wm, wn, acc);
}

// ---------------- GEMM core, f32 A reg-staged + cvt (projections, R8 exact) --
__device__ __forceinline__ void gemm_core_f32a(
    const float* __restrict__ Af,    // pre-offset to row0 of this tile
    const u16* __restrict__ Bt, u16* __restrict__ C,
    int N, int K, int row0, int col0,
    u16* As0, u16* As1, u16* Bs0, u16* Bs1)
{
  const int tid = threadIdx.x;
  const int wave = tid >> 6, lane = tid & 63;
  const int wm = wave >> 1, wn = wave & 1;
  f32x4 acc[4][4] = {};

  const int srow = lane >> 3, sslot = lane & 7;
  const int scol = ((sslot ^ srow) << 3);
  const float* gAf = Af + (size_t)((wave << 5) + srow) * K + scol;
  const u16*  gB  = Bt + (size_t)(col0 + (wave << 5) + srow) * K + scol;
  const int awbase = (lane << 3);

  float4 a0[4], a1[4];
  // prologue: tile 0
#pragma unroll
  for (int i = 0; i < 4; ++i) {
    const float* g = gAf + (size_t)(i << 3) * K;
    a0[i] = *(const float4*)g; a1[i] = *(const float4*)(g + 4);
  }
  stage_b(gB, Bs0, wave, K, 0);
#pragma unroll
  for (int i = 0; i < 4; ++i)
    cvt8_store(As0 + (((wave << 5) + (i << 3)) << 6) + awbase, a0[i], a1[i]);
  __syncthreads();

  u16 *asc = As0, *bsc = Bs0, *asn = As1, *bsn = Bs1;
  for (int k0 = 0; k0 < K; k0 += 64) {
    const bool more = (k0 + 64) < K;
    if (more) {
#pragma unroll
      for (int i = 0; i < 4; ++i) {
        const float* g = gAf + (size_t)(i << 3) * K + (k0 + 64);
        a0[i] = *(const float4*)g; a1[i] = *(const float4*)(g + 4);
      }
      stage_b(gB, bsn, wave, K, k0 + 64);   // B prefetch flies under MFMA
    }
    compute_step(asc, bsc, lane, wm, wn, acc);
    __syncthreads();                         // drains B gloads + A reg-loads
    if (more) {
#pragma unroll
      for (int i = 0; i < 4; ++i)
        cvt8_store(asn + (((wave << 5) + (i << 3)) << 6) + awbase, a0[i], a1[i]);
    }
    __syncthreads();                         // A writes visible to all waves
    u16* t_;
    t_ = asc; asc = asn; asn = t_;
    t_ = bsc; bsc = bsn; bsn = t_;
  }
  cwrite<0>(C, N, row0, col0, lane, wm, wn, acc);
}

// out projection (f32 out), 256 blocks, XCD-swizzled
template <int OUTF32>
__global__ __launch_bounds__(256, 2) void gemm_bt_kernel(
    const u16* __restrict__ A, const u16* __restrict__ Bt, void* __restrict__ C,
    int M, int N, int K)
{
  __shared__ u16 As[2][8192];
  __shared__ u16 Bs[2][8192];
  int bid = blockIdx.x;
  int t = (bid & 7) * 32 + (bid >> 3);      // bijective XCD chunk (256 = 8*32)
  const int bx = t & 7, by = t >> 3;
  gemm_core<OUTF32>(A, Bt, C, N, K, by << 7, bx << 7, As[0], As[1], Bs[0], Bs[1]);
}

// fused Q + K + V projections, f32 A direct (384 blocks), XCD-swizzled
__global__ __launch_bounds__(256, 2) void proj_kernel(
    const float* __restrict__ q, const float* __restrict__ k, const float* __restrict__ v,
    const u16* __restrict__ Wqt, const u16* __restrict__ Wkt, const u16* __restrict__ Wvt,
    u16* __restrict__ Qp, u16* __restrict__ KVp)
{
  __shared__ u16 As[2][8192];
  __shared__ u16 Bs[2][8192];
  int bid = blockIdx.x;
  int t = (bid & 7) * 48 + (bid >> 3);      // bijective XCD chunk (384 = 8*48)
  const float* Af; const u16* Bt; u16* C; int row0, col0;
  if (t < 256) {                            // Q projection: M=4096
    row0 = (t >> 3) << 7; col0 = (t & 7) << 7;
    Af = q + (size_t)row0 * 1024; Bt = Wqt; C = Qp;
  } else {                                  // K/V projections: M=2048
    int t2 = t - 256;
    row0 = (t2 >> 3) << 7; col0 = (t2 & 7) << 7;
    if (row0 < 1024) { Af = k + (size_t)row0 * 1024; Bt = Wkt; }
    else             { Af = v + (size_t)(row0 - 1024) * 1024; Bt = Wvt; }
    C = KVp;
  }
  gemm_core_f32a(Af, Bt, C, 1024, 1024, row0, col0, As[0], As[1], Bs[0], Bs[1]);
}

// ---------------- strided-local attention (MFMA, R8 core) --------------------
// Grid = 2048 blocks: [0,1024) attn tiles (XCD-swizzled), [1024,2048) Wo-transpose
// tiles (Wot is consumed only by the later outproj launch).
#define VTP 56   // Vt pitch (elems)
#define PLP 72   // Pl pitch (elems)
__global__ __launch_bounds__(256) void attn_kernel(
    const u16* __restrict__ Qp, const u16* __restrict__ Kp,
    const u16* __restrict__ Vp, u16* __restrict__ Ob,
    const float* __restrict__ W3, u16* __restrict__ T3)
{
  __shared__ u16 Ql[64 * 64];          // swizzled 128B rows (aliased by transpose tile)
  __shared__ u16 Kl[48 * 64];
  __shared__ u16 Vt[64 * VTP + 64];
  __shared__ u16 Pl[64 * PLP];

  const int bid = blockIdx.x;
  if (bid >= 1024) {                   // Wo transpose tile
    wtile_transpose(W3, T3, bid - 1024, (float*)Ql);
    return;
  }
  // XCD swizzle: XCD x gets t in [x*128,(x+1)*128) = one b, 4 heads, all jt
  const int t = (bid & 7) * 128 + (bid >> 3);
  const int jt = t & 31, h = (t >> 5) & 15, b = t >> 9;
  const int j0 = jt << 6;
  const int kbase = (j0 - 124) >> 2;
  const int tid = threadIdx.x;
  const int wave = tid >> 6, lane = tid & 63;

  const int srow = lane >> 3, sslot = lane & 7;
  const int scol = ((sslot ^ srow) << 3);
  for (int g = wave; g < 8; g += 4) {
    int r = (g << 3) + srow;
    const u16* ga = Qp + (((size_t)(b * 2048 + j0 + r)) << 10) + (h << 6) + scol;
    gload_lds16(ga, &Ql[g << 9]);
  }
  for (int g = wave; g < 6; g += 4) {
    int r = (g << 3) + srow;
    int key = kbase + r;
    key = key < 0 ? 0 : (key > 511 ? 511 : key);
    const u16* gk = Kp + (((size_t)(b * 512 + key)) << 10) + (h << 6) + scol;
    gload_lds16(gk, &Kl[g << 9]);
  }
  for (int idx = tid; idx < 48 * 8; idx += 256) {
    int row = idx >> 3, seg = idx & 7;
    int key = kbase + row;
    key = key < 0 ? 0 : (key > 511 ? 511 : key);
    uint4 x = *(const uint4*)(Vp + (((size_t)(b * 512 + key)) << 10) + (h << 6) + (seg << 3));
    int d0 = seg << 3;
    Vt[(d0 + 0) * VTP + row] = (u16)(x.x);
    Vt[(d0 + 1) * VTP + row] = (u16)(x.x >> 16);
    Vt[(d0 + 2) * VTP + row] = (u16)(x.y);
    Vt[(d0 + 3) * VTP + row] = (u16)(x.y >> 16);
    Vt[(d0 + 4) * VTP + row] = (u16)(x.z);
    Vt[(d0 + 5) * VTP + row] = (u16)(x.z >> 16);
    Vt[(d0 + 6) * VTP + row] = (u16)(x.w);
    Vt[(d0 + 7) * VTP + row] = (u16)(x.w >> 16);
  }
  if (tid < 64) *(uint4*)&Vt[tid * VTP + 48] = make_uint4(0, 0, 0, 0);
  else if (tid < 72) *(uint4*)&Vt[64 * VTP + ((tid - 64) << 3)] = make_uint4(0, 0, 0, 0);
  __syncthreads();

  f32x4 sacc[3] = {};
  const int frow_a = (wave << 4) + (lane & 15);
#pragma unroll
  for (int kk = 0; kk < 2; ++kk) {
    int colb = (kk << 6) + ((lane >> 4) << 4);
    bf16x8 aq = *(const bf16x8*)((const char*)Ql + (frow_a << 7) + (colb ^ ((frow_a & 7) << 4)));
#pragma unroll
    for (int nt = 0; nt < 3; ++nt) {
      int rk = (nt << 4) + (lane & 15);
      bf16x8 bk = *(const bf16x8*)((const char*)Kl + (rk << 7) + (colb ^ ((rk & 7) << 4)));
      sacc[nt] = __builtin_amdgcn_mfma_f32_16x16x32_bf16(aq, bk, sacc[nt], 0, 0, 0);
    }
  }

  const int rof = (wave << 2) + (lane >> 4);
  const int cb0 = lane & 15;
  bool vld[3]; float sc[3][4];
#pragma unroll
  for (int nt = 0; nt < 3; ++nt) {
    int c = cb0 + (nt << 4);
    vld[nt] = ((unsigned)(c - rof) < 32u) && (kbase + c >= 0);
#pragma unroll
    for (int r = 0; r < 4; ++r) sc[nt][r] = sacc[nt][r] * 0.125f;
  }
  float mx[4], rs[4];
#pragma unroll
  for (int r = 0; r < 4; ++r) {
    float m = -3.0e38f;
#pragma unroll
    for (int nt = 0; nt < 3; ++nt) m = vld[nt] ? fmaxf(m, sc[nt][r]) : m;
    m = fmaxf(m, __shfl_xor(m, 1));
    m = fmaxf(m, __shfl_xor(m, 2));
    m = fmaxf(m, __shfl_xor(m, 4));
    m = fmaxf(m, __shfl_xor(m, 8));
    mx[r] = m;
  }
#pragma unroll
  for (int r = 0; r < 4; ++r) {
    float s = 0.f;
#pragma unroll
    for (int nt = 0; nt < 3; ++nt) {
      float e = vld[nt] ? __expf(sc[nt][r] - mx[r]) : 0.f;
      sc[nt][r] = e;
      s += e;
    }
    s += __shfl_xor(s, 1);
    s += __shfl_xor(s, 2);
    s += __shfl_xor(s, 4);
    s += __shfl_xor(s, 8);
    rs[r] = 1.f / s;
  }
#pragma unroll
  for (int r = 0; r < 4; ++r) {
    int jq = (wave << 4) + ((lane >> 4) << 2) + r;
#pragma unroll
    for (int nt = 0; nt < 3; ++nt)
      Pl[jq * PLP + cb0 + (nt << 4)] = f2b(sc[nt][r] * rs[r]);
    Pl[jq * PLP + 48 + cb0] = 0;
  }
  __syncthreads();

  f32x4 oacc[4] = {};
#pragma unroll
  for (int kk = 0; kk < 2; ++kk) {
    int koff = (kk << 5) + ((lane >> 4) << 3);
    bf16x8 ap = *(const bf16x8*)&Pl[frow_a * PLP + koff];
#pragma unroll
    for (int nt = 0; nt < 4; ++nt) {
      int dr = (nt << 4) + (lane & 15);
      bf16x8 bv = *(const bf16x8*)&Vt[dr * VTP + koff];
      oacc[nt] = __builtin_amdgcn_mfma_f32_16x16x32_bf16(ap, bv, oacc[nt], 0, 0, 0);
    }
  }

#pragma unroll
  for (int nt = 0; nt < 4; ++nt) {
    int d = (nt << 4) + (lane & 15);
#pragma unroll
    for (int r = 0; r < 4; ++r) {
      int jq = (wave << 4) + ((lane >> 4) << 2) + r;
      Ob[(((size_t)(b * 2048 + j0 + jq)) << 10) + (h << 6) + d] = f2b(oacc[nt][r]);
    }
  }
}

extern "C" void kernel_launch(void* const* d_in, const int* in_sizes, int n_in,
                              void* d_out, int out_size, void* d_ws, size_t ws_size,
                              hipStream_t stream) {
  const float* q  = (const float*)d_in[0];
  const float* k  = (const float*)d_in[1];
  const float* v  = (const float*)d_in[2];
  const float* Wq = (const float*)d_in[3];
  const float* Wk = (const float*)d_in[4];
  const float* Wv = (const float*)d_in[5];
  const float* Wo = (const float*)d_in[6];

  char* ws = (char*)d_ws;
  const size_t MB = 1u << 20;
  u16* Wqt = (u16*)(ws + 0 * MB);    // 2 MB
  u16* Wkt = (u16*)(ws + 2 * MB);
  u16* Wvt = (u16*)(ws + 4 * MB);
  u16* Wot = (u16*)(ws + 6 * MB);
  u16* Qp  = (u16*)(ws + 8 * MB);    // 8 MB
  u16* Kp  = (u16*)(ws + 16 * MB);   // 2 MB  (Kp||Vp contiguous)
  u16* Vp  = (u16*)(ws + 18 * MB);   // 2 MB
  u16* Ob  = (u16*)(ws + 20 * MB);   // 8 MB  (total 28 MB)

  // 1) prep: transpose/convert Wq, Wk, Wv (Wo moved into attn launch)
  prep_kernel<<<3072, 256, 0, stream>>>(Wq, Wk, Wv, Wqt, Wkt, Wvt);
  // 2) all three projections, f32 A direct (R8 core)
  proj_kernel<<<384, 256, 0, stream>>>(q, k, v, Wqt, Wkt, Wvt, Qp, Kp);
  // 3) attention (XCD-swizzled) + Wo transpose blocks
  attn_kernel<<<2048, 256, 0, stream>>>(Qp, Kp, Vp, Ob, Wo, Wot);
  // 4) output projection (f32 out)
  gemm_bt_kernel<1><<<256, 256, 0, stream>>>(Ob, Wot, d_out, 4096, 1024, 1024);
}

// Round 11
// 58.065 us; speedup vs baseline: 1.0493x; 1.0030x over previous
//
#include <hip/hip_runtime.h>
#include <hip/hip_bf16.h>

typedef __bf16 bf16x8 __attribute__((ext_vector_type(8)));
typedef float  f32x4  __attribute__((ext_vector_type(4)));
typedef unsigned short u16;
typedef unsigned int   u32;

__device__ __forceinline__ u16 f2b(float x) {
  __bf16 b = (__bf16)x;
  return __builtin_bit_cast(u16, b);
}

__device__ __forceinline__ void gload_lds16(const u16* g, u16* l) {
  __builtin_amdgcn_global_load_lds(
      (const __attribute__((address_space(1))) void*)g,
      (__attribute__((address_space(3))) void*)l, 16, 0, 0);
}

// pack 8 f32 -> 8 bf16, one ds_write_b128
__device__ __forceinline__ void cvt8_store(u16* dst, float4 a, float4 b) {
  union { u16 u[8]; uint4 v; } r;
  r.u[0] = f2b(a.x); r.u[1] = f2b(a.y); r.u[2] = f2b(a.z); r.u[3] = f2b(a.w);
  r.u[4] = f2b(b.x); r.u[5] = f2b(b.y); r.u[6] = f2b(b.z); r.u[7] = f2b(b.w);
  *(uint4*)dst = r.v;
}

// shared 32x32 transpose-tile body
__device__ __forceinline__ void wtile_transpose(
    const float* __restrict__ W, u16* __restrict__ T, int rem, float* tile /*32x33*/)
{
  int tx = threadIdx.x & 31, ty = threadIdx.x >> 5;
  int c0 = (rem & 31) << 5, r0 = (rem >> 5) << 5;
#pragma unroll
  for (int i = 0; i < 4; ++i)
    tile[(ty + i * 8) * 33 + tx] = W[(size_t)(r0 + ty + i * 8) * 1024 + c0 + tx];
  __syncthreads();
#pragma unroll
  for (int i = 0; i < 4; ++i)
    T[(size_t)(c0 + ty + i * 8) * 1024 + r0 + tx] = f2b(tile[tx * 33 + ty + i * 8]);
}

// ---------------- prep: transpose + cvt Wq/Wk/Wv ------------------------------
__global__ __launch_bounds__(256) void prep_kernel(
    const float* __restrict__ W0, const float* __restrict__ W1,
    const float* __restrict__ W2,
    u16* __restrict__ T0, u16* __restrict__ T1, u16* __restrict__ T2)
{
  __shared__ float tile[32 * 33];
  int t = blockIdx.x;
  int z = t >> 10, rem = t & 1023;
  const float* W = (z == 0) ? W0 : (z == 1) ? W1 : W2;
  u16* T = (z == 0) ? T0 : (z == 1) ? T1 : T2;
  wtile_transpose(W, T, rem, tile);
}

// ---------------- shared GEMM pieces (R3-proven 128x128, 4 waves) ------------
__device__ __forceinline__ void compute_step(
    const u16* asc, const u16* bsc, int lane, int wm, int wn, f32x4 (&acc)[4][4])
{
#pragma unroll
  for (int kk = 0; kk < 2; ++kk) {
    bf16x8 af[4], bfr[4];
    int colb = (kk << 6) + ((lane >> 4) << 4);
#pragma unroll
    for (int m = 0; m < 4; ++m) {
      int r = (wm << 6) + (m << 4) + (lane & 15);
      af[m] = *(const bf16x8*)((const char*)asc + (r << 7) + (colb ^ ((r & 7) << 4)));
    }
#pragma unroll
    for (int n = 0; n < 4; ++n) {
      int r = (wn << 6) + (n << 4) + (lane & 15);
      bfr[n] = *(const bf16x8*)((const char*)bsc + (r << 7) + (colb ^ ((r & 7) << 4)));
    }
#pragma unroll
    for (int m = 0; m < 4; ++m)
#pragma unroll
      for (int n = 0; n < 4; ++n)
        acc[m][n] = __builtin_amdgcn_mfma_f32_16x16x32_bf16(af[m], bfr[n], acc[m][n], 0, 0, 0);
  }
}

__device__ __forceinline__ void stage_b(const u16* gB, u16* bs, int wave, int K, int k0) {
#pragma unroll
  for (int i = 0; i < 4; ++i) {
    int rb = (wave << 5) + (i << 3);
    gload_lds16(gB + (size_t)(i << 3) * K + k0, bs + (rb << 6));
  }
}

template <int OUTF32>
__device__ __forceinline__ void cwrite(
    void* C, int N, int row0, int col0, int lane, int wm, int wn, f32x4 (&acc)[4][4])
{
  const int crow = (lane >> 4) << 2;
  const int ccol = lane & 15;
#pragma unroll
  for (int m = 0; m < 4; ++m) {
#pragma unroll
    for (int n = 0; n < 4; ++n) {
      int r = row0 + (wm << 6) + (m << 4) + crow;
      int c = col0 + (wn << 6) + (n << 4) + ccol;
#pragma unroll
      for (int reg = 0; reg < 4; ++reg) {
        if (OUTF32) ((float*)C)[(size_t)(r + reg) * N + c] = acc[m][n][reg];
        else        ((u16*)C)[(size_t)(r + reg) * N + c] = f2b(acc[m][n][reg]);
      }
    }
  }
}

// ---------------- GEMM core, bf16 A via gload_lds (outproj) -----------------
template <int OUTF32>
__device__ __forceinline__ void gemm_core(
    const u16* __restrict__ A, const u16* __restrict__ Bt, void* __restrict__ C,
    int N, int K, int row0, int col0,
    u16* As0, u16* As1, u16* Bs0, u16* Bs1)
{
  const int tid = threadIdx.x;
  const int wave = tid >> 6, lane = tid & 63;
  const int wm = wave >> 1, wn = wave & 1;
  f32x4 acc[4][4] = {};

  const int srow = lane >> 3, sslot = lane & 7;
  const int scol = ((sslot ^ srow) << 3);
  const u16* gA = A + (size_t)(row0 + (wave << 5) + srow) * K + scol;
  const u16* gB = Bt + (size_t)(col0 + (wave << 5) + srow) * K + scol;

  stage_b(gA, As0, wave, K, 0);
  stage_b(gB, Bs0, wave, K, 0);
  __syncthreads();

  u16 *asc = As0, *bsc = Bs0, *asn = As1, *bsn = Bs1;
  for (int k0 = 0; k0 < K; k0 += 64) {
    if (k0 + 64 < K) {
      stage_b(gA, asn, wave, K, k0 + 64);
      stage_b(gB, bsn, wave, K, k0 + 64);
    }
    compute_step(asc, bsc, lane, wm, wn, acc);
    __syncthreads();
    u16* t_;
    t_ = asc; asc = asn; asn = t_;
    t_ = bsc; bsc = bsn; bsn = t_;
  }
  cwrite<OUTF32>(C, N, row0, col0, lane, wm, wn, acc);
}

// ---------------- GEMM core, f32 A reg-staged + cvt (projections, R8 exact) --
__device__ __forceinline__ void gemm_core_f32a(
    const float* __restrict__ Af,
    const u16* __restrict__ Bt, u16* __restrict__ C,
    int N, int K, int row0, int col0,
    u16* As0, u16* As1, u16* Bs0, u16* Bs1)
{
  const int tid = threadIdx.x;
  const int wave = tid >> 6, lane = tid & 63;
  const int wm = wave >> 1, wn = wave & 1;
  f32x4 acc[4][4] = {};

  const int srow = lane >> 3, sslot = lane & 7;
  const int scol = ((sslot ^ srow) << 3);
  const float* gAf = Af + (size_t)((wave << 5) + srow) * K + scol;
  const u16*  gB  = Bt + (size_t)(col0 + (wave << 5) + srow) * K + scol;
  const int awbase = (lane << 3);

  float4 a0[4], a1[4];
#pragma unroll
  for (int i = 0; i < 4; ++i) {
    const float* g = gAf + (size_t)(i << 3) * K;
    a0[i] = *(const float4*)g; a1[i] = *(const float4*)(g + 4);
  }
  stage_b(gB, Bs0, wave, K, 0);
#pragma unroll
  for (int i = 0; i < 4; ++i)
    cvt8_store(As0 + (((wave << 5) + (i << 3)) << 6) + awbase, a0[i], a1[i]);
  __syncthreads();

  u16 *asc = As0, *bsc = Bs0, *asn = As1, *bsn = Bs1;
  for (int k0 = 0; k0 < K; k0 += 64) {
    const bool more = (k0 + 64) < K;
    if (more) {
#pragma unroll
      for (int i = 0; i < 4; ++i) {
        const float* g = gAf + (size_t)(i << 3) * K + (k0 + 64);
        a0[i] = *(const float4*)g; a1[i] = *(const float4*)(g + 4);
      }
      stage_b(gB, bsn, wave, K, k0 + 64);
    }
    compute_step(asc, bsc, lane, wm, wn, acc);
    __syncthreads();
    if (more) {
#pragma unroll
      for (int i = 0; i < 4; ++i)
        cvt8_store(asn + (((wave << 5) + (i << 3)) << 6) + awbase, a0[i], a1[i]);
    }
    __syncthreads();
    u16* t_;
    t_ = asc; asc = asn; asn = t_;
    t_ = bsc; bsc = bsn; bsn = t_;
  }
  cwrite<0>(C, N, row0, col0, lane, wm, wn, acc);
}

// out projection (f32 out), 256 blocks, XCD-swizzled
template <int OUTF32>
__global__ __launch_bounds__(256, 2) void gemm_bt_kernel(
    const u16* __restrict__ A, const u16* __restrict__ Bt, void* __restrict__ C,
    int M, int N, int K)
{
  __shared__ u16 As[2][8192];
  __shared__ u16 Bs[2][8192];
  int bid = blockIdx.x;
  int t = (bid & 7) * 32 + (bid >> 3);
  const int bx = t & 7, by = t >> 3;
  gemm_core<OUTF32>(A, Bt, C, N, K, by << 7, bx << 7, As[0], As[1], Bs[0], Bs[1]);
}

// fused Q + K + V projections (384 GEMM blocks) + 1024 Wo-transpose tail blocks
__global__ __launch_bounds__(256, 2) void proj_kernel(
    const float* __restrict__ q, const float* __restrict__ k, const float* __restrict__ v,
    const u16* __restrict__ Wqt, const u16* __restrict__ Wkt, const u16* __restrict__ Wvt,
    u16* __restrict__ Qp, u16* __restrict__ KVp,
    const float* __restrict__ W3, u16* __restrict__ T3)
{
  __shared__ u16 As[2][8192];
  __shared__ u16 Bs[2][8192];
  int bid = blockIdx.x;
  if (bid >= 384) {                  // Wo transpose tile (consumed by later outproj)
    wtile_transpose(W3, T3, bid - 384, (float*)As);
    return;
  }
  int t = (bid & 7) * 48 + (bid >> 3);      // bijective XCD chunk (384 = 8*48)
  const float* Af; const u16* Bt; u16* C; int row0, col0;
  if (t < 256) {
    row0 = (t >> 3) << 7; col0 = (t & 7) << 7;
    Af = q + (size_t)row0 * 1024; Bt = Wqt; C = Qp;
  } else {
    int t2 = t - 256;
    row0 = (t2 >> 3) << 7; col0 = (t2 & 7) << 7;
    if (row0 < 1024) { Af = k + (size_t)row0 * 1024; Bt = Wkt; }
    else             { Af = v + (size_t)(row0 - 1024) * 1024; Bt = Wvt; }
    C = KVp;
  }
  gemm_core_f32a(Af, Bt, C, 1024, 1024, row0, col0, As[0], As[1], Bs[0], Bs[1]);
}

// ---------------- strided-local attention: 128 queries / block ---------------
// Block = (jt2, h, b): queries [j0, j0+128), j0 = jt2*128. kbase = (j0-124)/4.
// Sub-tile s (s = wave>>1) covers queries [64s, 64s+64) with slab-local cols
// c in [0,64) mapping to K rows kbase+16s+c. Valid iff (c-rof)<32 && kbase+16s+c>=0,
// rof = 8*(wave&1) + 4*mi + (lane>>4). K staged 80 rows; Vt 64 rows + zero cols.
#define VTP2 88   // Vt pitch (176B rows, 16B aligned, ~2-way banks)
#define PLP2 72   // Pl pitch (144B rows, 16B aligned, ~2-way banks)
__global__ __launch_bounds__(256) void attn_kernel(
    const u16* __restrict__ Qp, const u16* __restrict__ Kp,
    const u16* __restrict__ Vp, u16* __restrict__ Ob)
{
  __shared__ u16 Ql[128 * 64];         // swizzled 128B rows
  __shared__ u16 Kl[80 * 64];          // swizzled 128B rows
  __shared__ u16 Vt[64 * VTP2];        // V^T [d][slab col], cols 64..79 zeroed
  __shared__ u16 Pl[128 * PLP2];       // P [jq_local][c]

  const int bid = blockIdx.x;
  const int t = (bid & 7) * 64 + (bid >> 3);   // bijective XCD chunk (512 = 8*64)
  const int jt2 = t & 15, h = (t >> 4) & 15, b = t >> 8;
  const int j0 = jt2 << 7;
  const int kbase = (j0 - 124) >> 2;
  const int tid = threadIdx.x;
  const int wave = tid >> 6, lane = tid & 63;

  const int srow = lane >> 3, sslot = lane & 7;
  const int scol = ((sslot ^ srow) << 3);
  for (int g = wave; g < 16; g += 4) {
    int r = (g << 3) + srow;
    const u16* ga = Qp + (((size_t)(b * 2048 + j0 + r)) << 10) + (h << 6) + scol;
    gload_lds16(ga, &Ql[g << 9]);
  }
  for (int g = wave; g < 10; g += 4) {
    int r = (g << 3) + srow;
    int key = kbase + r;
    key = key < 0 ? 0 : (key > 511 ? 511 : key);
    const u16* gk = Kp + (((size_t)(b * 512 + key)) << 10) + (h << 6) + scol;
    gload_lds16(gk, &Kl[g << 9]);
  }
  for (int idx = tid; idx < 64 * 8; idx += 256) {
    int row = idx >> 3, seg = idx & 7;
    int key = kbase + row;
    key = key < 0 ? 0 : (key > 511 ? 511 : key);
    uint4 x = *(const uint4*)(Vp + (((size_t)(b * 512 + key)) << 10) + (h << 6) + (seg << 3));
    int d0 = seg << 3;
    Vt[(d0 + 0) * VTP2 + row] = (u16)(x.x);
    Vt[(d0 + 1) * VTP2 + row] = (u16)(x.x >> 16);
    Vt[(d0 + 2) * VTP2 + row] = (u16)(x.y);
    Vt[(d0 + 3) * VTP2 + row] = (u16)(x.y >> 16);
    Vt[(d0 + 4) * VTP2 + row] = (u16)(x.z);
    Vt[(d0 + 5) * VTP2 + row] = (u16)(x.z >> 16);
    Vt[(d0 + 6) * VTP2 + row] = (u16)(x.w);
    Vt[(d0 + 7) * VTP2 + row] = (u16)(x.w >> 16);
  }
  if (tid < 128) {  // zero Vt cols 64..79 (padding read by s=1's P cols 48..63)
    int row = tid >> 1, q = tid & 1;
    *(uint4*)&Vt[row * VTP2 + 64 + (q << 3)] = make_uint4(0, 0, 0, 0);
  }
  __syncthreads();

  const int s = wave >> 1;
  const int cb0 = lane & 15;
  const int frow0 = (wave << 5) + (lane & 15);

  // ---- QK^T: 2 m-frags x 4 n-tiles x 2 kk ----
  f32x4 sacc[2][4] = {};
#pragma unroll
  for (int kk = 0; kk < 2; ++kk) {
    int colb = (kk << 6) + ((lane >> 4) << 4);
    bf16x8 aq[2];
#pragma unroll
    for (int mi = 0; mi < 2; ++mi) {
      int fr = frow0 + (mi << 4);
      aq[mi] = *(const bf16x8*)((const char*)Ql + (fr << 7) + (colb ^ ((fr & 7) << 4)));
    }
#pragma unroll
    for (int nt = 0; nt < 4; ++nt) {
      int rk = (s << 4) + (nt << 4) + (lane & 15);
      bf16x8 bk = *(const bf16x8*)((const char*)Kl + (rk << 7) + (colb ^ ((rk & 7) << 4)));
#pragma unroll
      for (int mi = 0; mi < 2; ++mi)
        sacc[mi][nt] = __builtin_amdgcn_mfma_f32_16x16x32_bf16(aq[mi], bk, sacc[mi][nt], 0, 0, 0);
    }
  }

  // ---- masked softmax (in-register) + P write ----
#pragma unroll
  for (int mi = 0; mi < 2; ++mi) {
    const int rof = ((wave & 1) << 3) + (mi << 2) + (lane >> 4);
    bool vld[4]; float sc[4][4];
#pragma unroll
    for (int nt = 0; nt < 4; ++nt) {
      int c = (nt << 4) + cb0;
      vld[nt] = ((unsigned)(c - rof) < 32u) && (kbase + (s << 4) + c >= 0);
#pragma unroll
      for (int r = 0; r < 4; ++r) sc[nt][r] = sacc[mi][nt][r] * 0.125f;
    }
#pragma unroll
    for (int r = 0; r < 4; ++r) {
      float m = -3.0e38f;
#pragma unroll
      for (int nt = 0; nt < 4; ++nt) m = vld[nt] ? fmaxf(m, sc[nt][r]) : m;
      m = fmaxf(m, __shfl_xor(m, 1));
      m = fmaxf(m, __shfl_xor(m, 2));
      m = fmaxf(m, __shfl_xor(m, 4));
      m = fmaxf(m, __shfl_xor(m, 8));
      float ssum = 0.f;
      float e[4];
#pragma unroll
      for (int nt = 0; nt < 4; ++nt) {
        e[nt] = vld[nt] ? __expf(sc[nt][r] - m) : 0.f;
        ssum += e[nt];
      }
      ssum += __shfl_xor(ssum, 1);
      ssum += __shfl_xor(ssum, 2);
      ssum += __shfl_xor(ssum, 4);
      ssum += __shfl_xor(ssum, 8);
      float rs = 1.f / ssum;
      int jq = (wave << 5) + (mi << 4) + ((lane >> 4) << 2) + r;
#pragma unroll
      for (int nt = 0; nt < 4; ++nt)
        Pl[jq * PLP2 + (nt << 4) + cb0] = f2b(e[nt] * rs);
    }
  }
  __syncthreads();

  // ---- PV: O = P . V (K=64 local cols, V col-offset 16s) ----
  f32x4 oacc[2][4] = {};
#pragma unroll
  for (int kk = 0; kk < 2; ++kk) {
    int koff = (kk << 5) + ((lane >> 4) << 3);
    bf16x8 ap[2];
#pragma unroll
    for (int mi = 0; mi < 2; ++mi)
      ap[mi] = *(const bf16x8*)&Pl[(frow0 + (mi << 4)) * PLP2 + koff];
#pragma unroll
    for (int nt = 0; nt < 4; ++nt) {
      int dr = (nt << 4) + (lane & 15);
      bf16x8 bv = *(const bf16x8*)&Vt[dr * VTP2 + (s << 4) + koff];
#pragma unroll
      for (int mi = 0; mi < 2; ++mi)
        oacc[mi][nt] = __builtin_amdgcn_mfma_f32_16x16x32_bf16(ap[mi], bv, oacc[mi][nt], 0, 0, 0);
    }
  }

#pragma unroll
  for (int mi = 0; mi < 2; ++mi)
#pragma unroll
    for (int nt = 0; nt < 4; ++nt) {
      int d = (nt << 4) + (lane & 15);
#pragma unroll
      for (int r = 0; r < 4; ++r) {
        int jq = (wave << 5) + (mi << 4) + ((lane >> 4) << 2) + r;
        Ob[(((size_t)(b * 2048 + j0 + jq)) << 10) + (h << 6) + d] = f2b(oacc[mi][nt][r]);
      }
    }
}

extern "C" void kernel_launch(void* const* d_in, const int* in_sizes, int n_in,
                              void* d_out, int out_size, void* d_ws, size_t ws_size,
                              hipStream_t stream) {
  const float* q  = (const float*)d_in[0];
  const float* k  = (const float*)d_in[1];
  const float* v  = (const float*)d_in[2];
  const float* Wq = (const float*)d_in[3];
  const float* Wk = (const float*)d_in[4];
  const float* Wv = (const float*)d_in[5];
  const float* Wo = (const float*)d_in[6];

  char* ws = (char*)d_ws;
  const size_t MB = 1u << 20;
  u16* Wqt = (u16*)(ws + 0 * MB);    // 2 MB
  u16* Wkt = (u16*)(ws + 2 * MB);
  u16* Wvt = (u16*)(ws + 4 * MB);
  u16* Wot = (u16*)(ws + 6 * MB);
  u16* Qp  = (u16*)(ws + 8 * MB);    // 8 MB
  u16* Kp  = (u16*)(ws + 16 * MB);   // 2 MB  (Kp||Vp contiguous)
  u16* Vp  = (u16*)(ws + 18 * MB);   // 2 MB
  u16* Ob  = (u16*)(ws + 20 * MB);   // 8 MB  (total 28 MB)

  // 1) prep: transpose/convert Wq, Wk, Wv
  prep_kernel<<<3072, 256, 0, stream>>>(Wq, Wk, Wv, Wqt, Wkt, Wvt);
  // 2) projections (f32 A direct) + Wo-transpose tail blocks
  proj_kernel<<<1408, 256, 0, stream>>>(q, k, v, Wqt, Wkt, Wvt, Qp, Kp, Wo, Wot);
  // 3) attention: 128 queries/block, shared K/V window, XCD-swizzled
  attn_kernel<<<512, 256, 0, stream>>>(Qp, Kp, Vp, Ob);
  // 4) output projection (f32 out)
  gemm_bt_kernel<1><<<256, 256, 0, stream>>>(Ob, Wot, d_out, 4096, 1024, 1024);
}